// Round 10
// baseline (852.377 us; speedup 1.0000x reference)
//
#include <hip/hip_runtime.h>

constexpr int NN = 50000;    // nodes
constexpr int NE = 1600000;  // edges
constexpr int NG = 128;      // graphs
constexpr int BSTRIDE = 96;  // adj bucket slots per node (deg~Poisson(32), max~58)

constexpr int FILL_PASSES = 8;
constexpr int NODES_PER_PASS = 6250;              // 8*6250 = 50000
constexpr int BLOCKS_PER_PASS = (NE + 255) / 256; // 6250 (6250*256 == NE exactly)

// workspace layout (bytes)
#define OFF_CNT      0            // int[50000] atomic cursor; == deg after fill
#define OFF_GSUM     200000       // float[128*20]
#define OFF_GCNT     210240       // float[128]
#define OFF_TICKET   210752       // int[8] per-pass chunk tickets
#define ZERO_BYTES   210784
#define OFF_ADJ      210784       // ushort[50000*96] = 9.6MB bucketed adjacency
#define OFF_X1F      9810784      // fp8[50000*128] rows 128B-aligned (6.4MB)
#define OFF_X2B      16210784     // bf16[50000*32] rows 64B (3.2MB)
// end: 19410784 (~19MB)

typedef float v2f __attribute__((ext_vector_type(2)));

// ---- bf16 helpers ---------------------------------------------------------
__device__ __forceinline__ unsigned short f2bf(float x) {      // RNE
    unsigned int v = __float_as_uint(x);
    return (unsigned short)((v + 0x7FFFu + ((v >> 16) & 1u)) >> 16);
}
__device__ __forceinline__ float bflo(unsigned int u) { return __uint_as_float(u << 16); }
__device__ __forceinline__ float bfhi(unsigned int u) { return __uint_as_float(u & 0xFFFF0000u); }

__device__ __forceinline__ int get_xcc_id() {
    int x;
    asm volatile("s_getreg_b32 %0, hwreg(HW_REG_XCC_ID)" : "=s"(x));
    return x & 7;
}

// ---- bucketed fill, XCD-PINNED dst-range passes ---------------------------
// Block claims a chunk of the pass matching its physical XCD (ticket per
// pass). All writes to adj slice p then come from one XCD -> lines stay in
// that L2 until fully written (R9: blockIdx%8 left WRITE at 6x array size).
// Coverage proof: 50000 blocks, 50000 chunks, each block claims <=1 chunk,
// and can only exit empty if all 50000 chunks are claimed by other blocks
// (impossible: only 49999 others) -> every chunk processed under ANY
// block->XCD mapping; garbage XCC_ID degrades perf only.
__global__ void k_fill(const int* __restrict__ src, const int* __restrict__ dst,
                       int* __restrict__ cnt, int* __restrict__ ticket,
                       unsigned short* __restrict__ adj) {
    __shared__ int s_chunk, s_pass;
    if (threadIdx.x == 0) {
        const int p0 = get_xcc_id();
        int mychunk = -1, myp = 0;
        for (int k = 0; k < FILL_PASSES; ++k) {
            const int p = (p0 + k) & 7;
            const int tt = atomicAdd(&ticket[p], 1);
            if (tt < BLOCKS_PER_PASS) { mychunk = tt; myp = p; break; }
        }
        s_chunk = mychunk; s_pass = myp;
    }
    __syncthreads();
    const int chunkI = s_chunk;
    if (chunkI < 0) return;
    const int pass = s_pass;
    const int i = chunkI * 256 + threadIdx.x;
    const int d = dst[i];
    const int lo = pass * NODES_PER_PASS;
    if (d >= lo && d < lo + NODES_PER_PASS) {
        const int p = atomicAdd(&cnt[d], 1);
        if (p < BSTRIDE) adj[d * BSTRIDE + p] = (unsigned short)src[i];
    }
}

// ---- X1f = fp8_e4m3(feat @ W1)  (50000x128 @ 128x100), row = 128 fp8 -----
__global__ __launch_bounds__(256) void k_gemm1(const float4* __restrict__ feat4,
                                               const float* __restrict__ W1,
                                               unsigned int* __restrict__ X1f) {
    const int t = threadIdx.x;
    if (t >= 250) return;
    const int cg = t % 25;            // cols [4cg, 4cg+4)
    const int nq = t / 25;            // node quad within block
    const int node0 = blockIdx.x * 40 + nq * 4;
    const int col0 = cg * 4;

    float acc[4][4];
#pragma unroll
    for (int i = 0; i < 4; ++i)
#pragma unroll
        for (int j = 0; j < 4; ++j) acc[i][j] = 0.f;

    for (int k4 = 0; k4 < 32; ++k4) {
        float4 f[4];
#pragma unroll
        for (int i = 0; i < 4; ++i) f[i] = feat4[(node0 + i) * 32 + k4];
        float4 wr[4];
#pragma unroll
        for (int kk = 0; kk < 4; ++kk)
            wr[kk] = *(const float4*)(W1 + (k4 * 4 + kk) * 100 + col0);
#pragma unroll
        for (int kk = 0; kk < 4; ++kk) {
#pragma unroll
            for (int i = 0; i < 4; ++i) {
                const float fv = (kk == 0) ? f[i].x
                               : (kk == 1) ? f[i].y
                               : (kk == 2) ? f[i].z : f[i].w;
                acc[i][0] += fv * wr[kk].x;
                acc[i][1] += fv * wr[kk].y;
                acc[i][2] += fv * wr[kk].z;
                acc[i][3] += fv * wr[kk].w;
            }
        }
    }
#pragma unroll
    for (int i = 0; i < 4; ++i) {
        int u = 0;
        u = __builtin_amdgcn_cvt_pk_fp8_f32(acc[i][0], acc[i][1], u, false);
        u = __builtin_amdgcn_cvt_pk_fp8_f32(acc[i][2], acc[i][3], u, true);
        X1f[(node0 + i) * 32 + cg] = (unsigned int)u;
        if (cg == 24) {  // zero pad cols 100..127 (read by agg1 lane q=6)
#pragma unroll
            for (int z = 25; z < 32; ++z) X1f[(node0 + i) * 32 + z] = 0u;
        }
    }
}

// ---- FUSED layer-1 aggregate + gemm2 --------------------------------------
// Block = 448 threads = 64 nodes x 7 lanes.
// Phase 1: lane (n,q) gathers 16B (16 fp8) of each in-edge row (1 line/edge),
//          means + bias + relu -> LDS H-tile [64][104] f32.
// Phase 2: X2b[node*16+j] = bf16x2( Hrow @ W2[:,2j:2j+2] ), j<10.
// Saves the 40MB H1 global round-trip and one launch.
__global__ __launch_bounds__(448) void k_agg1(const uint4* __restrict__ X1u,
                                              const int* __restrict__ cnt,
                                              const unsigned short* __restrict__ adj,
                                              const float* __restrict__ b1,
                                              const float* __restrict__ W2,
                                              unsigned int* __restrict__ X2b) {
    __shared__ float lh[64 * 104];
    const int t = threadIdx.x;
    const int nl = t / 7;                 // local node 0..63
    const int q = t - nl * 7;             // cols [16q, 16q+16)
    const int node = blockIdx.x * 64 + nl;

    if (node < NN) {
        const int d = cnt[node];
        const unsigned short* ab = adj + node * BSTRIDE;
        float a[16];
#pragma unroll
        for (int j = 0; j < 16; ++j) a[j] = 0.f;

#define ACC4(UU, B) { v2f l_ = __builtin_amdgcn_cvt_pk_f32_fp8((int)(UU), false); \
                      v2f h_ = __builtin_amdgcn_cvt_pk_f32_fp8((int)(UU), true);  \
                      a[B+0] += l_.x; a[B+1] += l_.y; a[B+2] += h_.x; a[B+3] += h_.y; }
#define SET4(UU, B) { v2f l_ = __builtin_amdgcn_cvt_pk_f32_fp8((int)(UU), false); \
                      v2f h_ = __builtin_amdgcn_cvt_pk_f32_fp8((int)(UU), true);  \
                      a[B+0] = l_.x; a[B+1] = l_.y; a[B+2] = h_.x; a[B+3] = h_.y; }
        for (int i = 0; i < d; ++i) {
            const int s = (int)ab[i];           // broadcast across 7-lane group
            const uint4 u = X1u[s * 8 + q];     // 16B of the 128B row
            ACC4(u.x, 0) ACC4(u.y, 4) ACC4(u.z, 8) ACC4(u.w, 12)
        }
        if (d > 0) {
            const float inv = 1.f / (float)d;
#pragma unroll
            for (int j = 0; j < 16; ++j) a[j] *= inv;
        } else {
            const uint4 u = X1u[node * 8 + q];
            SET4(u.x, 0) SET4(u.y, 4) SET4(u.z, 8) SET4(u.w, 12)
        }
#undef ACC4
#undef SET4
        const int col0 = 16 * q;
        float* hrow = lh + nl * 104 + col0;
        const int nc = (q < 6) ? 16 : 4;      // q==6 contributes cols 96..99
#pragma unroll
        for (int v = 0; v < 4; ++v) {
            if (4 * v < nc) {
                float4 r;
                r.x = fmaxf(a[4 * v + 0] + b1[col0 + 4 * v + 0], 0.f);
                r.y = fmaxf(a[4 * v + 1] + b1[col0 + 4 * v + 1], 0.f);
                r.z = fmaxf(a[4 * v + 2] + b1[col0 + 4 * v + 2], 0.f);
                r.w = fmaxf(a[4 * v + 3] + b1[col0 + 4 * v + 3], 0.f);
                *(float4*)(hrow + 4 * v) = r;
            }
        }
    }
    __syncthreads();

    // phase 2: 64 nodes x 10 col-pairs = 640 items over 448 threads
    for (int idx = t; idx < 640; idx += 448) {
        const int n2 = idx / 10;
        const int j = idx - n2 * 10;
        const int gnode = blockIdx.x * 64 + n2;
        if (gnode >= NN) break;
        const float* h = lh + n2 * 104;
        float a0 = 0.f, a1 = 0.f;
#pragma unroll 5
        for (int k = 0; k < 100; ++k) {
            const float hv = h[k];
            a0 += hv * W2[k * 20 + 2 * j];
            a1 += hv * W2[k * 20 + 2 * j + 1];
        }
        X2b[gnode * 16 + j] = (unsigned int)f2bf(a0) | ((unsigned int)f2bf(a1) << 16);
    }
}

// ---- layer-2 aggregate + LDS per-graph reduce -----------------------------
__global__ __launch_bounds__(320) void k_agg2(const uint2* __restrict__ X2v,
                                              const int* __restrict__ cnt,
                                              const unsigned short* __restrict__ adj,
                                              const float* __restrict__ b2,
                                              const int* __restrict__ graph_id,
                                              float* __restrict__ g_sum,
                                              float* __restrict__ g_cnt) {
    __shared__ float lsum[NG * 20];
    __shared__ float lcnt[NG];
    const int t = threadIdx.x;
    for (int i = t; i < NG * 20; i += 320) lsum[i] = 0.f;
    for (int i = t; i < NG; i += 320) lcnt[i] = 0.f;
    __syncthreads();

    const int node = blockIdx.x * 64 + t / 5;
    const int q = t % 5;                      // cols [4q, 4q+4)
    if (node < NN) {
        const int d = cnt[node];
        const unsigned short* ab = adj + node * BSTRIDE;
        float ax = 0.f, ay = 0.f, az = 0.f, aw = 0.f;
        for (int i = 0; i < d; ++i) {
            const int s = (int)ab[i];
            const uint2 u = X2v[s * 8 + q];   // 8B of the 64B bf16 row
            ax += bflo(u.x); ay += bfhi(u.x);
            az += bflo(u.y); aw += bfhi(u.y);
        }
        if (d > 0) {
            const float inv = 1.f / (float)d;
            ax *= inv; ay *= inv; az *= inv; aw *= inv;
        } else {
            const uint2 u = X2v[node * 8 + q];
            ax = bflo(u.x); ay = bfhi(u.x);
            az = bflo(u.y); aw = bfhi(u.y);
        }
        const int col0 = 4 * q;
        const float hx = fmaxf(ax + b2[col0 + 0], 0.f);
        const float hy = fmaxf(ay + b2[col0 + 1], 0.f);
        const float hz = fmaxf(az + b2[col0 + 2], 0.f);
        const float hw = fmaxf(aw + b2[col0 + 3], 0.f);
        const int g = graph_id[node];
        atomicAdd(&lsum[g * 20 + col0 + 0], hx);
        atomicAdd(&lsum[g * 20 + col0 + 1], hy);
        atomicAdd(&lsum[g * 20 + col0 + 2], hz);
        atomicAdd(&lsum[g * 20 + col0 + 3], hw);
        if (q == 0) atomicAdd(&lcnt[g], 1.f);
    }
    __syncthreads();

    const int first = blockIdx.x * 64;
    const int last = min(first + 63, NN - 1);
    const int gmin = graph_id[first];
    const int span = graph_id[last] - gmin + 1;
    for (int idx = t; idx < span * 20; idx += 320) {
        const int g = gmin + idx / 20;
        const int c = idx - (idx / 20) * 20;
        const float v = lsum[g * 20 + c];
        if (v != 0.f) atomicAdd(&g_sum[g * 20 + c], v);
    }
    for (int idx = t; idx < span; idx += 320) {
        const float v = lcnt[gmin + idx];
        if (v != 0.f) atomicAdd(&g_cnt[gmin + idx], v);
    }
}

// ---- final: hg = g_sum/max(cnt,1); out = relu([hg,self]@Wf1+bf1)@Wf2+bf2 --
__global__ __launch_bounds__(128) void k_final(const float* __restrict__ g_sum,
                                               const float* __restrict__ g_cnt,
                                               const float* __restrict__ self_feat,
                                               const float* __restrict__ Wf1,
                                               const float* __restrict__ bf1,
                                               const float* __restrict__ Wf2,
                                               const float* __restrict__ bf2,
                                               float* __restrict__ out) {
    const int g = threadIdx.x;  // 128 graphs, one block
    float fused[36];
    const float cnt = fmaxf(g_cnt[g], 1.f);
    const float inv = 1.f / cnt;
#pragma unroll
    for (int j = 0; j < 20; ++j) fused[j] = g_sum[g * 20 + j] * inv;
#pragma unroll
    for (int j = 0; j < 16; ++j) fused[20 + j] = self_feat[g * 16 + j];
    float o = bf2[0];
#pragma unroll
    for (int i = 0; i < 10; ++i) {
        float t = bf1[i];
#pragma unroll
        for (int k = 0; k < 36; ++k) t += fused[k] * Wf1[k * 10 + i];
        o += fmaxf(t, 0.f) * Wf2[i];
    }
    out[g] = o;
}

extern "C" void kernel_launch(void* const* d_in, const int* in_sizes, int n_in,
                              void* d_out, int out_size, void* d_ws, size_t ws_size,
                              hipStream_t stream) {
    const float* feat      = (const float*)d_in[0];
    const float* self_feat = (const float*)d_in[1];
    const int*   src       = (const int*)d_in[2];
    const int*   dst       = (const int*)d_in[3];
    const int*   graph_id  = (const int*)d_in[4];
    const float* W1        = (const float*)d_in[5];
    const float* b1        = (const float*)d_in[6];
    const float* W2        = (const float*)d_in[7];
    const float* b2        = (const float*)d_in[8];
    const float* Wf1       = (const float*)d_in[9];
    const float* bf1       = (const float*)d_in[10];
    const float* Wf2       = (const float*)d_in[11];
    const float* bf2       = (const float*)d_in[12];

    char* w = (char*)d_ws;
    int*            cnt      = (int*)(w + OFF_CNT);
    float*          g_sum    = (float*)(w + OFF_GSUM);
    float*          g_cnt    = (float*)(w + OFF_GCNT);
    int*            ticket   = (int*)(w + OFF_TICKET);
    unsigned short* adj      = (unsigned short*)(w + OFF_ADJ);
    unsigned int*   X1f      = (unsigned int*)(w + OFF_X1F);
    unsigned int*   X2b      = (unsigned int*)(w + OFF_X2B);

    hipMemsetAsync(w, 0, ZERO_BYTES, stream);  // cnt + g_sum + g_cnt + ticket

    k_fill<<<FILL_PASSES * BLOCKS_PER_PASS, 256, 0, stream>>>(src, dst, cnt,
                                                              ticket, adj);
    k_gemm1<<<1250, 256, 0, stream>>>((const float4*)feat, W1, X1f);
    k_agg1<<<(NN + 63) / 64, 448, 0, stream>>>((const uint4*)X1f, cnt,
                                               adj, b1, W2, X2b);
    k_agg2<<<(NN + 63) / 64, 320, 0, stream>>>((const uint2*)X2b, cnt,
                                               adj, b2, graph_id, g_sum, g_cnt);
    k_final<<<1, 128, 0, stream>>>(g_sum, g_cnt, self_feat, Wf1, bf1, Wf2, bf2,
                                   (float*)d_out);
}

// Round 11
// 337.732 us; speedup vs baseline: 2.5238x; 2.5238x over previous
//
#include <hip/hip_runtime.h>

constexpr int NN = 50000;    // nodes
constexpr int NE = 1600000;  // edges
constexpr int NG = 128;      // graphs
constexpr int BSTRIDE = 96;  // adj bucket slots per node (deg~Poisson(32), max~58)

// k_fill: 8 concurrent dst-range passes, pass = blockIdx % 8 (R9-proven).
// R10 lesson: do NOT serialize block startup on shared atomic tickets —
// one hot ticket line cost 8x. blockIdx%8 needs no coordination.
constexpr int FILL_PASSES = 8;
constexpr int NODES_PER_PASS = 6250;              // 8*6250 = 50000
constexpr int BLOCKS_PER_PASS = (NE + 255) / 256; // 6250 (6250*256 == NE exactly)

// workspace layout (bytes)
#define OFF_CNT      0            // int[50000] atomic cursor; == deg after fill
#define OFF_GSUM     200000       // float[128*20]
#define OFF_GCNT     210240       // float[128]
#define ZERO_BYTES   210752
#define OFF_ADJ      210752       // ushort[50000*96] = 9.6MB bucketed adjacency
#define OFF_X1F      9810752      // fp8[50000*128] rows 128B-aligned (6.4MB)
#define OFF_X2B      16210752     // bf16[50000*32] rows 64B (3.2MB)
// end: 19410752 (~19MB)

typedef float v2f __attribute__((ext_vector_type(2)));

// ---- bf16 helpers ---------------------------------------------------------
__device__ __forceinline__ unsigned short f2bf(float x) {      // RNE
    unsigned int v = __float_as_uint(x);
    return (unsigned short)((v + 0x7FFFu + ((v >> 16) & 1u)) >> 16);
}
__device__ __forceinline__ float bflo(unsigned int u) { return __uint_as_float(u << 16); }
__device__ __forceinline__ float bfhi(unsigned int u) { return __uint_as_float(u & 0xFFFF0000u); }

// ---- bucketed fill, dst-range passes + non-temporal streams ---------------
// pass p handles dst in [p*6250, (p+1)*6250): adj slice 1.2MB + cursor 25KB.
// src/dst reads are non-temporal so the ~13MB/pass read stream does NOT
// evict the pass's dirty adj slice from L2 (R10 analysis: stream-evictions
// caused ~6x adj writeback amplification, 59MB for a 9.6MB array).
__global__ void k_fill(const int* __restrict__ src, const int* __restrict__ dst,
                       int* __restrict__ cnt, unsigned short* __restrict__ adj) {
    const int pass = blockIdx.x & 7;
    const int chunk = blockIdx.x >> 3;
    const int i = chunk * 256 + threadIdx.x;
    if (i >= NE) return;
    const int d = __builtin_nontemporal_load(&dst[i]);
    const int lo = pass * NODES_PER_PASS;
    if (d >= lo && d < lo + NODES_PER_PASS) {
        const int s = __builtin_nontemporal_load(&src[i]);
        const int p = atomicAdd(&cnt[d], 1);
        if (p < BSTRIDE) adj[d * BSTRIDE + p] = (unsigned short)s;
    }
}

// ---- X1f = fp8_e4m3(feat @ W1)  (50000x128 @ 128x100), row = 128 fp8 -----
__global__ __launch_bounds__(256) void k_gemm1(const float4* __restrict__ feat4,
                                               const float* __restrict__ W1,
                                               unsigned int* __restrict__ X1f) {
    const int t = threadIdx.x;
    if (t >= 250) return;
    const int cg = t % 25;            // cols [4cg, 4cg+4)
    const int nq = t / 25;            // node quad within block
    const int node0 = blockIdx.x * 40 + nq * 4;
    const int col0 = cg * 4;

    float acc[4][4];
#pragma unroll
    for (int i = 0; i < 4; ++i)
#pragma unroll
        for (int j = 0; j < 4; ++j) acc[i][j] = 0.f;

    for (int k4 = 0; k4 < 32; ++k4) {
        float4 f[4];
#pragma unroll
        for (int i = 0; i < 4; ++i) f[i] = feat4[(node0 + i) * 32 + k4];
        float4 wr[4];
#pragma unroll
        for (int kk = 0; kk < 4; ++kk)
            wr[kk] = *(const float4*)(W1 + (k4 * 4 + kk) * 100 + col0);
#pragma unroll
        for (int kk = 0; kk < 4; ++kk) {
#pragma unroll
            for (int i = 0; i < 4; ++i) {
                const float fv = (kk == 0) ? f[i].x
                               : (kk == 1) ? f[i].y
                               : (kk == 2) ? f[i].z : f[i].w;
                acc[i][0] += fv * wr[kk].x;
                acc[i][1] += fv * wr[kk].y;
                acc[i][2] += fv * wr[kk].z;
                acc[i][3] += fv * wr[kk].w;
            }
        }
    }
#pragma unroll
    for (int i = 0; i < 4; ++i) {
        int u = 0;
        u = __builtin_amdgcn_cvt_pk_fp8_f32(acc[i][0], acc[i][1], u, false);
        u = __builtin_amdgcn_cvt_pk_fp8_f32(acc[i][2], acc[i][3], u, true);
        X1f[(node0 + i) * 32 + cg] = (unsigned int)u;
        if (cg == 24) {  // zero pad cols 100..127 (read by agg1 lane q=6)
#pragma unroll
            for (int z = 25; z < 32; ++z) X1f[(node0 + i) * 32 + z] = 0u;
        }
    }
}

// ---- FUSED layer-1 aggregate + gemm2 --------------------------------------
// Block = 448 threads = 64 nodes x 7 lanes.
// Phase 1: lane (n,q) gathers 16B (16 fp8) of each in-edge row (1 line/edge),
//          means + bias + relu -> LDS H-tile [64][104] f32.
// Phase 2: X2b[node*16+j] = bf16x2( Hrow @ W2[:,2j:2j+2] ), j<10.
__global__ __launch_bounds__(448) void k_agg1(const uint4* __restrict__ X1u,
                                              const int* __restrict__ cnt,
                                              const unsigned short* __restrict__ adj,
                                              const float* __restrict__ b1,
                                              const float* __restrict__ W2,
                                              unsigned int* __restrict__ X2b) {
    __shared__ float lh[64 * 104];
    const int t = threadIdx.x;
    const int nl = t / 7;                 // local node 0..63
    const int q = t - nl * 7;             // cols [16q, 16q+16)
    const int node = blockIdx.x * 64 + nl;

    if (node < NN) {
        const int d = cnt[node];
        const unsigned short* ab = adj + node * BSTRIDE;
        float a[16];
#pragma unroll
        for (int j = 0; j < 16; ++j) a[j] = 0.f;

#define ACC4(UU, B) { v2f l_ = __builtin_amdgcn_cvt_pk_f32_fp8((int)(UU), false); \
                      v2f h_ = __builtin_amdgcn_cvt_pk_f32_fp8((int)(UU), true);  \
                      a[B+0] += l_.x; a[B+1] += l_.y; a[B+2] += h_.x; a[B+3] += h_.y; }
#define SET4(UU, B) { v2f l_ = __builtin_amdgcn_cvt_pk_f32_fp8((int)(UU), false); \
                      v2f h_ = __builtin_amdgcn_cvt_pk_f32_fp8((int)(UU), true);  \
                      a[B+0] = l_.x; a[B+1] = l_.y; a[B+2] = h_.x; a[B+3] = h_.y; }
        for (int i = 0; i < d; ++i) {
            const int s = (int)ab[i];           // broadcast across 7-lane group
            const uint4 u = X1u[s * 8 + q];     // 16B of the 128B row
            ACC4(u.x, 0) ACC4(u.y, 4) ACC4(u.z, 8) ACC4(u.w, 12)
        }
        if (d > 0) {
            const float inv = 1.f / (float)d;
#pragma unroll
            for (int j = 0; j < 16; ++j) a[j] *= inv;
        } else {
            const uint4 u = X1u[node * 8 + q];
            SET4(u.x, 0) SET4(u.y, 4) SET4(u.z, 8) SET4(u.w, 12)
        }
#undef ACC4
#undef SET4
        const int col0 = 16 * q;
        float* hrow = lh + nl * 104 + col0;
        const int nc = (q < 6) ? 16 : 4;      // q==6 contributes cols 96..99
#pragma unroll
        for (int v = 0; v < 4; ++v) {
            if (4 * v < nc) {
                float4 r;
                r.x = fmaxf(a[4 * v + 0] + b1[col0 + 4 * v + 0], 0.f);
                r.y = fmaxf(a[4 * v + 1] + b1[col0 + 4 * v + 1], 0.f);
                r.z = fmaxf(a[4 * v + 2] + b1[col0 + 4 * v + 2], 0.f);
                r.w = fmaxf(a[4 * v + 3] + b1[col0 + 4 * v + 3], 0.f);
                *(float4*)(hrow + 4 * v) = r;
            }
        }
    }
    __syncthreads();

    // phase 2: 64 nodes x 10 col-pairs = 640 items over 448 threads
    for (int idx = t; idx < 640; idx += 448) {
        const int n2 = idx / 10;
        const int j = idx - n2 * 10;
        const int gnode = blockIdx.x * 64 + n2;
        if (gnode >= NN) break;
        const float* h = lh + n2 * 104;
        float a0 = 0.f, a1 = 0.f;
#pragma unroll 5
        for (int k = 0; k < 100; ++k) {
            const float hv = h[k];
            a0 += hv * W2[k * 20 + 2 * j];
            a1 += hv * W2[k * 20 + 2 * j + 1];
        }
        X2b[gnode * 16 + j] = (unsigned int)f2bf(a0) | ((unsigned int)f2bf(a1) << 16);
    }
}

// ---- layer-2 aggregate + LDS per-graph reduce -----------------------------
__global__ __launch_bounds__(320) void k_agg2(const uint2* __restrict__ X2v,
                                              const int* __restrict__ cnt,
                                              const unsigned short* __restrict__ adj,
                                              const float* __restrict__ b2,
                                              const int* __restrict__ graph_id,
                                              float* __restrict__ g_sum,
                                              float* __restrict__ g_cnt) {
    __shared__ float lsum[NG * 20];
    __shared__ float lcnt[NG];
    const int t = threadIdx.x;
    for (int i = t; i < NG * 20; i += 320) lsum[i] = 0.f;
    for (int i = t; i < NG; i += 320) lcnt[i] = 0.f;
    __syncthreads();

    const int node = blockIdx.x * 64 + t / 5;
    const int q = t % 5;                      // cols [4q, 4q+4)
    if (node < NN) {
        const int d = cnt[node];
        const unsigned short* ab = adj + node * BSTRIDE;
        float ax = 0.f, ay = 0.f, az = 0.f, aw = 0.f;
        for (int i = 0; i < d; ++i) {
            const int s = (int)ab[i];
            const uint2 u = X2v[s * 8 + q];   // 8B of the 64B bf16 row
            ax += bflo(u.x); ay += bfhi(u.x);
            az += bflo(u.y); aw += bfhi(u.y);
        }
        if (d > 0) {
            const float inv = 1.f / (float)d;
            ax *= inv; ay *= inv; az *= inv; aw *= inv;
        } else {
            const uint2 u = X2v[node * 8 + q];
            ax = bflo(u.x); ay = bfhi(u.x);
            az = bflo(u.y); aw = bfhi(u.y);
        }
        const int col0 = 4 * q;
        const float hx = fmaxf(ax + b2[col0 + 0], 0.f);
        const float hy = fmaxf(ay + b2[col0 + 1], 0.f);
        const float hz = fmaxf(az + b2[col0 + 2], 0.f);
        const float hw = fmaxf(aw + b2[col0 + 3], 0.f);
        const int g = graph_id[node];
        atomicAdd(&lsum[g * 20 + col0 + 0], hx);
        atomicAdd(&lsum[g * 20 + col0 + 1], hy);
        atomicAdd(&lsum[g * 20 + col0 + 2], hz);
        atomicAdd(&lsum[g * 20 + col0 + 3], hw);
        if (q == 0) atomicAdd(&lcnt[g], 1.f);
    }
    __syncthreads();

    const int first = blockIdx.x * 64;
    const int last = min(first + 63, NN - 1);
    const int gmin = graph_id[first];
    const int span = graph_id[last] - gmin + 1;
    for (int idx = t; idx < span * 20; idx += 320) {
        const int g = gmin + idx / 20;
        const int c = idx - (idx / 20) * 20;
        const float v = lsum[g * 20 + c];
        if (v != 0.f) atomicAdd(&g_sum[g * 20 + c], v);
    }
    for (int idx = t; idx < span; idx += 320) {
        const float v = lcnt[gmin + idx];
        if (v != 0.f) atomicAdd(&g_cnt[gmin + idx], v);
    }
}

// ---- final: hg = g_sum/max(cnt,1); out = relu([hg,self]@Wf1+bf1)@Wf2+bf2 --
__global__ __launch_bounds__(128) void k_final(const float* __restrict__ g_sum,
                                               const float* __restrict__ g_cnt,
                                               const float* __restrict__ self_feat,
                                               const float* __restrict__ Wf1,
                                               const float* __restrict__ bf1,
                                               const float* __restrict__ Wf2,
                                               const float* __restrict__ bf2,
                                               float* __restrict__ out) {
    const int g = threadIdx.x;  // 128 graphs, one block
    float fused[36];
    const float cnt = fmaxf(g_cnt[g], 1.f);
    const float inv = 1.f / cnt;
#pragma unroll
    for (int j = 0; j < 20; ++j) fused[j] = g_sum[g * 20 + j] * inv;
#pragma unroll
    for (int j = 0; j < 16; ++j) fused[20 + j] = self_feat[g * 16 + j];
    float o = bf2[0];
#pragma unroll
    for (int i = 0; i < 10; ++i) {
        float t = bf1[i];
#pragma unroll
        for (int k = 0; k < 36; ++k) t += fused[k] * Wf1[k * 10 + i];
        o += fmaxf(t, 0.f) * Wf2[i];
    }
    out[g] = o;
}

extern "C" void kernel_launch(void* const* d_in, const int* in_sizes, int n_in,
                              void* d_out, int out_size, void* d_ws, size_t ws_size,
                              hipStream_t stream) {
    const float* feat      = (const float*)d_in[0];
    const float* self_feat = (const float*)d_in[1];
    const int*   src       = (const int*)d_in[2];
    const int*   dst       = (const int*)d_in[3];
    const int*   graph_id  = (const int*)d_in[4];
    const float* W1        = (const float*)d_in[5];
    const float* b1        = (const float*)d_in[6];
    const float* W2        = (const float*)d_in[7];
    const float* b2        = (const float*)d_in[8];
    const float* Wf1       = (const float*)d_in[9];
    const float* bf1       = (const float*)d_in[10];
    const float* Wf2       = (const float*)d_in[11];
    const float* bf2       = (const float*)d_in[12];

    char* w = (char*)d_ws;
    int*            cnt      = (int*)(w + OFF_CNT);
    float*          g_sum    = (float*)(w + OFF_GSUM);
    float*          g_cnt    = (float*)(w + OFF_GCNT);
    unsigned short* adj      = (unsigned short*)(w + OFF_ADJ);
    unsigned int*   X1f      = (unsigned int*)(w + OFF_X1F);
    unsigned int*   X2b      = (unsigned int*)(w + OFF_X2B);

    hipMemsetAsync(w, 0, ZERO_BYTES, stream);  // cnt + g_sum + g_cnt

    k_fill<<<FILL_PASSES * BLOCKS_PER_PASS, 256, 0, stream>>>(src, dst, cnt, adj);
    k_gemm1<<<1250, 256, 0, stream>>>((const float4*)feat, W1, X1f);
    k_agg1<<<(NN + 63) / 64, 448, 0, stream>>>((const uint4*)X1f, cnt,
                                               adj, b1, W2, X2b);
    k_agg2<<<(NN + 63) / 64, 320, 0, stream>>>((const uint2*)X2b, cnt,
                                               adj, b2, graph_id, g_sum, g_cnt);
    k_final<<<1, 128, 0, stream>>>(g_sum, g_cnt, self_feat, Wf1, bf1, Wf2, bf2,
                                   (float*)d_out);
}